// Round 1
// baseline (777.386 us; speedup 1.0000x reference)
//
#include <hip/hip_runtime.h>
#include <math.h>

#define C_CH 54
#define CP   64      // candidate row stride: [0..53]=cand, 54=candsq, 55=tcand, 56=libmean
#define NT   20
#define NM   6
#define NK   120     // NM * NT
#define BLK  256
#define PPT  2                     // pixels per thread
#define PIX_PER_BLK (BLK * PPT)    // 512

typedef float sf16 __attribute__((ext_vector_type(16)));
typedef float sf8  __attribute__((ext_vector_type(8)));

// ---------------- prep: candidate table (CP=64 rows) into workspace ----------------
__global__ __launch_bounds__(256) void hadar_prep(
    const float* __restrict__ s_sky, const float* __restrict__ s_ground,
    const float* __restrict__ library, const float* __restrict__ wg,
    float* __restrict__ cand)
{
    __shared__ float xamb[C_CH];
    __shared__ float tc[NT];
    __shared__ float lm[NM];
    const int tid = threadIdx.x;
    if (tid < NT) tc[tid] = 250.0f + (float)tid * (100.0f / 19.0f);
    if (tid < C_CH) xamb[tid] = 0.5f * s_sky[tid] + 0.5f * s_ground[tid];
    if (tid < NM) {
        float s = 0.0f;
        for (int c = 0; c < C_CH; ++c) s += library[tid * C_CH + c];
        lm[tid] = s / (float)C_CH;
    }
    __syncthreads();

    const float c1 = 1.191042e-8f, c2 = 1.4387752f;
    for (int idx = tid; idx < NK * CP; idx += 256) {
        const int k = idx >> 6, c = idx & 63;
        float v = 0.0f;
        if (c < C_CH) {
            const int m = k / NT, t = k - m * NT;
            const float nu = wg[c];
            const float B = c1 * nu * nu * nu / expm1f(c2 * nu / tc[t]);
            const float e = library[m * C_CH + c];
            v = e * B + (1.0f - e) * xamb[c];
        }
        cand[idx] = v;
    }
    __syncthreads();

    if (tid < NK) {
        float s = 0.0f;
        for (int c = 0; c < C_CH; ++c) { float v = cand[tid * CP + c]; s += v * v; }
        const int m = tid / NT, t = tid - m * NT;
        cand[tid * CP + 54] = s;        // candsq
        cand[tid * CP + 55] = tc[t];    // best_t value for this k
        cand[tid * CP + 56] = lm[m];    // texture value for this k
    }
}

// element c of the current candidate row held in SGPRs (c is compile-time after unroll)
#define CE(c) ((c) < 16 ? q0[(c)] : (c) < 32 ? q1[(c)-16] : (c) < 48 ? q2[(c)-32] : q3[(c)-48])

// ---------------- main: TWO pixels per thread, candidate rows via scalar loads ----------
// Per-candidate cost: 4 s_load + one lgkmcnt(0) wait now feeds 108 FMAs (2 pixels)
// instead of 54 — the serialized SMEM latency is amortized 2x. SGPR footprint of
// the candidate fragment is unchanged. Epilogue: block-coalesced writer for the
// two [*,54] output arrays via LDS-held argmin indices (4 lines/store-instr
// instead of ~64 with the old per-thread float2 pattern).
__global__ __launch_bounds__(BLK) void hadar_main(
    const float* __restrict__ s_obs,
    const float* __restrict__ library,
    const float* __restrict__ cand,
    float* __restrict__ out, float* __restrict__ partials, int N)
{
    const int tid = threadIdx.x;
    const long long base = (long long)blockIdx.x * PIX_PER_BLK;
    const long long n0 = base + tid;
    const long long n1 = base + BLK + tid;
    const bool v0 = (n0 < N);
    const bool v1 = (n1 < N);

    // pixel rows in VGPRs (2 x 54 floats)
    float row0[C_CH], row1[C_CH];
    if (v0) {
        const float2* rp = (const float2*)(s_obs + n0 * C_CH);
        #pragma unroll
        for (int i = 0; i < C_CH / 2; ++i) {
            float2 w = rp[i];
            row0[2 * i] = w.x; row0[2 * i + 1] = w.y;
        }
    } else {
        #pragma unroll
        for (int c = 0; c < C_CH; ++c) row0[c] = 0.0f;
    }
    if (v1) {
        const float2* rp = (const float2*)(s_obs + n1 * C_CH);
        #pragma unroll
        for (int i = 0; i < C_CH / 2; ++i) {
            float2 w = rp[i];
            row1[2 * i] = w.x; row1[2 * i + 1] = w.y;
        }
    } else {
        #pragma unroll
        for (int c = 0; c < C_CH; ++c) row1[c] = 0.0f;
    }

    // ssq, same sequential order as before
    float ssq0 = 0.0f, ssq1 = 0.0f;
    #pragma unroll
    for (int c = 0; c < C_CH; ++c) ssq0 += row0[c] * row0[c];
    #pragma unroll
    for (int c = 0; c < C_CH; ++c) ssq1 += row1[c] * row1[c];

    float bl0 = 3.4e38f, bl1 = 3.4e38f;
    int bk0 = NK, bk1 = NK;   // sentinel larger than any real k

    // per-wave rotation: 15 distinct starts, step 8 (15*8 = 120).
    const int wid = __builtin_amdgcn_readfirstlane(tid >> 6);
    const int rot = (int)((blockIdx.x * 4u + (unsigned)wid) % 15u) * 8;

    int kk = rot;
    const float* pk = cand + (size_t)rot * CP;
    #pragma unroll 1
    for (int i = 0; i < NK; ++i) {
        sf16 q0, q1, q2;
        sf8  q3;
        asm volatile("s_load_dwordx16 %0, %1, 0x0"  : "=s"(q0) : "s"(pk));
        asm volatile("s_load_dwordx16 %0, %1, 0x40" : "=s"(q1) : "s"(pk));
        asm volatile("s_load_dwordx16 %0, %1, 0x80" : "=s"(q2) : "s"(pk));
        asm volatile("s_load_dwordx8  %0, %1, 0xc0" : "=s"(q3) : "s"(pk));
        // tie the wait to the loaded values so consumers can't be hoisted above it
        asm volatile("s_waitcnt lgkmcnt(0)" : "+s"(q0), "+s"(q1), "+s"(q2), "+s"(q3));

        float a0[4] = {0.f, 0.f, 0.f, 0.f};
        float a1[4] = {0.f, 0.f, 0.f, 0.f};
        #pragma unroll
        for (int c = 0; c < C_CH; ++c) {
            const float ce = CE(c);
            a0[c & 3] += row0[c] * ce;
            a1[c & 3] += row1[c] * ce;
        }
        const float sq = q3[6];   // slot 54 = candsq
        const float d0 = (a0[0] + a0[1]) + (a0[2] + a0[3]);
        const float d1 = (a1[0] + a1[1]) + (a1[2] + a1[3]);
        const float l0 = (ssq0 - 2.0f * d0) + sq;
        const float l1 = (ssq1 - 2.0f * d1) + sq;
        // lexicographic (loss, k) min == first-min in k order
        if (l0 < bl0 || (l0 == bl0 && kk < bk0)) { bl0 = l0; bk0 = kk; }
        if (l1 < bl1 || (l1 == bl1 && kk < bk1)) { bl1 = l1; bk1 = kk; }

        ++kk; pk += CP;
        if (kk == NK) { kk = 0; pk = cand; }
    }

    // clamp invalid pixels so table indexing below stays in-bounds
    if (!v0) bk0 = 0;
    if (!v1) bk1 = 0;

    const size_t NN = (size_t)N;
    const size_t NC = (size_t)C_CH * NN;

    // ---- small per-pixel outputs (coalesced) ----
    if (v0) {
        const float* cr = cand + (size_t)bk0 * CP;
        out[n0] = cr[55];                      // best_t
        out[NN + NC + n0] = 0.5f;              // best_v
        out[2 * NN + NC + n0] = 0.0f;          // beta
        out[3 * NN + NC + n0] = cr[56];        // texture
    }
    if (v1) {
        const float* cr = cand + (size_t)bk1 * CP;
        out[n1] = cr[55];
        out[NN + NC + n1] = 0.5f;
        out[2 * NN + NC + n1] = 0.0f;
        out[3 * NN + NC + n1] = cr[56];
    }

    // ---- block-coalesced writer for best_e and s_recon ----
    __shared__ int2 bkm[PIX_PER_BLK];   // {cand row offset, library row offset}
    bkm[tid]       = make_int2(bk0 * CP, (bk0 / NT) * C_CH);
    bkm[tid + BLK] = make_int2(bk1 * CP, (bk1 / NT) * C_CH);

    float lsum = (v0 ? bl0 : 0.0f) + (v1 ? bl1 : 0.0f);
    __syncthreads();

    {
        float* __restrict__ be = out + NN + (size_t)base * C_CH;
        float* __restrict__ sr = out + 4 * NN + NC + (size_t)base * C_CH;
        int p = tid / C_CH;
        int c = tid - p * C_CH;
        #pragma unroll 4
        for (int j = tid; j < PIX_PER_BLK * C_CH; j += BLK) {   // 108 iterations
            const int2 o = bkm[p];
            const float ev = library[o.y + c];   // L1-resident (1.3 KB)
            const float sv = cand[o.x + c];      // L1/L2-resident (30 KB)
            if (base + p < N) { be[j] = ev; sr[j] = sv; }
            // j += 256 == 4 rows + 40 channels
            p += 4; c += 40;
            if (c >= C_CH) { c -= C_CH; ++p; }
        }
    }

    // ---- deterministic block reduction of best_loss sum ----
    __shared__ float red[BLK];
    red[tid] = lsum;
    __syncthreads();
    #pragma unroll
    for (int s = BLK / 2; s > 0; s >>= 1) {
        if (tid < s) red[tid] += red[tid + s];
        __syncthreads();
    }
    if (tid == 0) partials[blockIdx.x] = red[0];
}

// ---------------- final reduce: objective = mean(best_loss) ----------------
__global__ __launch_bounds__(256) void hadar_reduce(
    const float* __restrict__ partials, int nb, float* __restrict__ obj_out, float invN)
{
    __shared__ float red[256];
    float s = 0.0f;
    for (int i = threadIdx.x; i < nb; i += 256) s += partials[i];
    red[threadIdx.x] = s;
    __syncthreads();
    #pragma unroll
    for (int st = 128; st > 0; st >>= 1) {
        if (threadIdx.x < st) red[threadIdx.x] += red[threadIdx.x + st];
        __syncthreads();
    }
    if (threadIdx.x == 0) *obj_out = red[0] * invN;
}

extern "C" void kernel_launch(void* const* d_in, const int* in_sizes, int n_in,
                              void* d_out, int out_size, void* d_ws, size_t ws_size,
                              hipStream_t stream)
{
    const float* s_obs    = (const float*)d_in[0];
    const float* s_sky    = (const float*)d_in[1];
    const float* s_ground = (const float*)d_in[2];
    const float* library  = (const float*)d_in[3];
    const float* wg       = (const float*)d_in[4];
    float* out = (float*)d_out;

    const int N  = in_sizes[0] / C_CH;
    const int nb = (N + PIX_PER_BLK - 1) / PIX_PER_BLK;

    float* ws       = (float*)d_ws;
    float* cand     = ws;              // NK*CP = 7680 floats
    float* partials = ws + 8192;       // nb floats

    hadar_prep<<<1, 256, 0, stream>>>(s_sky, s_ground, library, wg, cand);
    hadar_main<<<nb, BLK, 0, stream>>>(s_obs, library, cand, out, partials, N);

    const size_t NN = (size_t)N;
    float* obj_out = out + 4 * NN + 2 * (size_t)C_CH * NN;
    hadar_reduce<<<1, 256, 0, stream>>>(partials, nb, obj_out, 1.0f / (float)N);
}